// Round 7
// baseline (3600.586 us; speedup 1.0000x reference)
//
#include <hip/hip_runtime.h>
#include <hip/hip_bf16.h>
#include <stdint.h>

// Problem constants
#define NBATCH 512
#define NE 32     // electrons
#define NA 36     // all particles
#define BAS 32    // basis
#define KD 128    // KDIM
#define ED 128    // EDIM
#define HK 64     // HID_K
#define HO 128    // HID_O
#define NT 3      // interactions
#define TIL 32    // pairs per tile
#define NTILES 35 // 1120 / 32

typedef uint16_t u16;
typedef uint32_t u32;

__device__ __forceinline__ float bf2f(u16 u) {
    return __uint_as_float(((u32)u) << 16);
}
__device__ __forceinline__ u16 f2bf(float f) {
    u32 x = __float_as_uint(f);
    u32 r = x + 0x7fffu + ((x >> 16) & 1u); // RNE
    return (u16)(r >> 16);
}
__device__ __forceinline__ void ld8(const float* p, float* f) {
    float4 v0 = *(const float4*)p;
    float4 v1 = *(const float4*)(p + 4);
    f[0] = v0.x; f[1] = v0.y; f[2] = v0.z; f[3] = v0.w;
    f[4] = v1.x; f[5] = v1.y; f[6] = v1.z; f[7] = v1.w;
}
// softplus(x) - log(2), numerically stable
__device__ __forceinline__ float ssp_f(float x) {
    float ax = fabsf(x);
    return fmaxf(x, 0.0f) + __logf(1.0f + __expf(-ax)) - 0.6931471805599453f;
}

// One block per batch element. 512 threads = 8 waves. LDS 62720 B -> 2 blocks/CU.
// ALL inputs f32 (reference dtypes), dict order. OUTPUT f32 (reference returns
// jnp.float32 — the round-0..6 failures were bf16 writes into a float* buffer).
__global__ __launch_bounds__(512, 4) void schnet_kernel(
    const float* __restrict__ db_g,   // dists_basis (512,32,36,32)
    const float* __restrict__ ee_g,   // embedding_elec (32,128)
    const float* __restrict__ en_g,   // embedding_nuc (4,128)
    const float* __restrict__ w1_g,   // kernel_w1 (3,64,32)
    const float* __restrict__ b1_g,   // kernel_b1 (3,64)
    const float* __restrict__ w2_g,   // kernel_w2 (3,128,64)
    const float* __restrict__ b2_g,   // kernel_b2 (3,128)
    const float* __restrict__ win_g,  // embed_in_w (3,128,128)
    const float* __restrict__ wo1_g,  // embed_out_w1 (3,128,128)
    const float* __restrict__ bo1_g,  // embed_out_b1 (3,128)
    const float* __restrict__ wo2_g,  // embed_out_w2 (3,128,128)
    const float* __restrict__ bo2_g,  // embed_out_b2 (3,128)
    float* __restrict__ out_g)        // (512,32,128) f32
{
    __shared__ __align__(16) float xs[NE][ED];
    __shared__ __align__(16) u16 zs[NA][KD];     // bf16-compressed (LDS budget)
    __shared__ __align__(16) float zacc[NE][KD];
    __shared__ __align__(16) float uni[4096];
    __shared__ __align__(16) u16 w1l[BAS * HK];  // [i][c] i-major, bf16
    __shared__ float b1l[HK];

    float* dbt = uni;            // [TIL][36]
    float* ht = uni + TIL * 36;  // [TIL][64]
    float* h2 = uni;             // [NE][128] in D phase

    const int tid = threadIdx.x;
    const int b = blockIdx.x;

    const int k = tid & 127;   // column / k-dim lane
    const int rg = tid >> 7;   // 0..3 row/e group
    const int mh = rg & 1;     // m-half for GEMM2 split
    const int rhalf = rg >> 1; // row half for GEMM2

    // ---- init xs from embedding_elec, zs nuc rows from embedding_nuc ----
    {
        int base = tid * 8; // 4096 elems
        float f[8];
        ld8(ee_g + base, f);
#pragma unroll
        for (int i = 0; i < 8; i++)
            xs[(base + i) >> 7][(base + i) & 127] = f[i];
    }
    if (tid < 64) {
        int base = tid * 8; // 512 elems -> zs rows 32..35
        float f[8];
        ld8(en_g + base, f);
#pragma unroll
        for (int i = 0; i < 8; i++) zs[32][base + i] = f2bf(f[i]);
    }
    __syncthreads();

    for (int t = 0; t < NT; t++) {
        // ---- per-t weight staging ----
        {
            int idx = tid * 4; // over (i,c), c fastest; 2048 elems
            int i0 = idx >> 6;
            int c0 = idx & 63;
#pragma unroll
            for (int q = 0; q < 4; q++)
                w1l[i0 * 64 + c0 + q] = f2bf(w1_g[(t * HK + (c0 + q)) * BAS + i0]);
        }
        if (tid < HK) b1l[tid] = b1_g[t * HK + tid];

        // w2 rows into registers: thread (k, mh) holds w2[t][k][mh*32 .. +32)
        float w2r[32];
        {
            const float* p = w2_g + (size_t)(t * KD + k) * HK + mh * 32;
#pragma unroll
            for (int q = 0; q < 4; q++) ld8(p + q * 8, &w2r[q * 8]);
        }
        const float b2k = (mh == 0) ? b2_g[t * KD + k] : 0.0f;

        // ---- zero zacc ----
        {
            float4 z4 = {0.f, 0.f, 0.f, 0.f};
            ((float4*)zacc)[tid] = z4;
            ((float4*)zacc)[tid + 512] = z4;
        }

        // ---- A: zs[e][k] = sum_d xs[e][d] * win[t][k][d] ----
        {
            const float* wrow = win_g + (size_t)(t * KD + k) * ED;
#pragma unroll
            for (int pass = 0; pass < 2; pass++) {
                int e0 = rg * 8 + pass * 4;
                float acc[4] = {0.f, 0.f, 0.f, 0.f};
                for (int d8 = 0; d8 < ED; d8 += 8) {
                    float wf[8];
                    ld8(wrow + d8, wf);
#pragma unroll
                    for (int q = 0; q < 4; q++) {
                        float4 xa = *(const float4*)&xs[e0 + q][d8];
                        float4 xb = *(const float4*)&xs[e0 + q][d8 + 4];
                        acc[q] += xa.x * wf[0] + xa.y * wf[1] + xa.z * wf[2] +
                                  xa.w * wf[3] + xb.x * wf[4] + xb.y * wf[5] +
                                  xb.z * wf[6] + xb.w * wf[7];
                    }
                }
#pragma unroll
                for (int q = 0; q < 4; q++) zs[e0 + q][k] = f2bf(acc[q]);
            }
        }
        __syncthreads();

        // ---- pair loop: 35 tiles of 32 pairs ----
        for (int tile = 0; tile < NTILES; tile++) {
            int p0 = tile * TIL;
            if (tid < 128) { // stage db tile (32 rows x 32 basis)
                int r = tid >> 2;
                int c8 = (tid & 3) * 8;
                int p = p0 + r;
                int e = p / 35;
                int jj = p - e * 35;
                int j = jj + (jj >= e);
                const float* src = db_g + (((size_t)b * NE + e) * NA + j) * BAS + c8;
                float f[8];
                ld8(src, f);
#pragma unroll
                for (int q = 0; q < 8; q++) dbt[r * 36 + c8 + q] = f[q];
            }
            __syncthreads();

            // GEMM1: ht[r][c] = ssp(b1[c] + sum_i dbt[r][i]*w1[c][i])
            {
                int c = tid & 63;
                int rq = tid >> 6; // 0..7
                int r0 = rq * 4;
                float a0 = 0.f, a1 = 0.f, a2 = 0.f, a3 = 0.f;
                for (int i = 0; i < BAS; i++) {
                    float w = bf2f(w1l[i * 64 + c]);
                    a0 += dbt[(r0 + 0) * 36 + i] * w;
                    a1 += dbt[(r0 + 1) * 36 + i] * w;
                    a2 += dbt[(r0 + 2) * 36 + i] * w;
                    a3 += dbt[(r0 + 3) * 36 + i] * w;
                }
                float bb = b1l[c];
                ht[(r0 + 0) * 64 + c] = ssp_f(a0 + bb);
                ht[(r0 + 1) * 64 + c] = ssp_f(a1 + bb);
                ht[(r0 + 2) * 64 + c] = ssp_f(a2 + bb);
                ht[(r0 + 3) * 64 + c] = ssp_f(a3 + bb);
            }
            __syncthreads();

            // GEMM2 + consume: Ws[p][k] = b2[k] + sum_m h[p][m]*w2[k][m];
            // zacc[e][k] += Ws * zs[j][k]  (split over mh halves, distributive)
            {
                const float* hb = ht + mh * 32;
#pragma unroll
                for (int rb = 0; rb < 4; rb++) {
                    int r0 = rhalf * 16 + rb * 4;
                    float a[4] = {b2k, b2k, b2k, b2k};
#pragma unroll
                    for (int m4 = 0; m4 < 32; m4 += 4) {
#pragma unroll
                        for (int rr = 0; rr < 4; rr++) {
                            float4 h4 = *(const float4*)(hb + (r0 + rr) * 64 + m4);
                            a[rr] += h4.x * w2r[m4] + h4.y * w2r[m4 + 1] +
                                     h4.z * w2r[m4 + 2] + h4.w * w2r[m4 + 3];
                        }
                    }
#pragma unroll
                    for (int rr = 0; rr < 4; rr++) {
                        int p = p0 + r0 + rr;
                        int e = p / 35;
                        int jj = p - e * 35;
                        int j = jj + (jj >= e);
                        float zv = bf2f(zs[j][k]);
                        atomicAdd(&zacc[e][k], a[rr] * zv);
                    }
                }
            }
            __syncthreads();
        }

        // ---- D1: h2[e][ho] = ssp(bo1[ho] + sum_kk zacc[e][kk]*wo1[ho][kk]) ----
        {
            const float* wrow = wo1_g + (size_t)(t * HO + k) * KD;
            float bo1v = bo1_g[t * HO + k];
#pragma unroll
            for (int pass = 0; pass < 2; pass++) {
                int e0 = rg * 8 + pass * 4;
                float acc[4] = {0.f, 0.f, 0.f, 0.f};
                for (int d8 = 0; d8 < KD; d8 += 8) {
                    float wf[8];
                    ld8(wrow + d8, wf);
#pragma unroll
                    for (int q = 0; q < 4; q++) {
                        float4 za = *(const float4*)&zacc[e0 + q][d8];
                        float4 zb = *(const float4*)&zacc[e0 + q][d8 + 4];
                        acc[q] += za.x * wf[0] + za.y * wf[1] + za.z * wf[2] +
                                  za.w * wf[3] + zb.x * wf[4] + zb.y * wf[5] +
                                  zb.z * wf[6] + zb.w * wf[7];
                    }
                }
#pragma unroll
                for (int q = 0; q < 4; q++)
                    h2[(e0 + q) * 128 + k] = ssp_f(acc[q] + bo1v);
            }
        }
        __syncthreads();

        // ---- D2: xs[e][d] += bo2[d] + sum_h h2[e][h]*wo2[d][h] ----
        {
            const float* wrow = wo2_g + (size_t)(t * ED + k) * HO;
            float bo2v = bo2_g[t * ED + k];
#pragma unroll
            for (int pass = 0; pass < 2; pass++) {
                int e0 = rg * 8 + pass * 4;
                float acc[4] = {0.f, 0.f, 0.f, 0.f};
                for (int h8 = 0; h8 < HO; h8 += 8) {
                    float wf[8];
                    ld8(wrow + h8, wf);
#pragma unroll
                    for (int q = 0; q < 4; q++) {
                        float4 ha = *(const float4*)&h2[(e0 + q) * 128 + h8];
                        float4 hb4 = *(const float4*)&h2[(e0 + q) * 128 + h8 + 4];
                        acc[q] += ha.x * wf[0] + ha.y * wf[1] + ha.z * wf[2] +
                                  ha.w * wf[3] + hb4.x * wf[4] + hb4.y * wf[5] +
                                  hb4.z * wf[6] + hb4.w * wf[7];
                    }
                }
#pragma unroll
                for (int q = 0; q < 4; q++) xs[e0 + q][k] += acc[q] + bo2v;
            }
        }
        __syncthreads();
    }

    // ---- write out (f32 — the reference's output dtype) ----
    {
        size_t base = (size_t)b * (NE * ED);
#pragma unroll
        for (int ii = 0; ii < 8; ii++) {
            int idx = ii * 512 + tid;
            out_g[base + idx] = xs[idx >> 7][idx & 127];
        }
    }
}

extern "C" void kernel_launch(void* const* d_in, const int* in_sizes, int n_in,
                              void* d_out, int out_size, void* d_ws, size_t ws_size,
                              hipStream_t stream) {
    schnet_kernel<<<NBATCH, 512, 0, stream>>>(
        (const float*)d_in[0], (const float*)d_in[1], (const float*)d_in[2],
        (const float*)d_in[3], (const float*)d_in[4], (const float*)d_in[5],
        (const float*)d_in[6], (const float*)d_in[7], (const float*)d_in[8],
        (const float*)d_in[9], (const float*)d_in[10], (const float*)d_in[11],
        (float*)d_out);
}

// Round 8
// 1344.020 us; speedup vs baseline: 2.6790x; 2.6790x over previous
//
#include <hip/hip_runtime.h>
#include <stdint.h>

#define NBATCH 512
#define NE 32
#define NA 36
#define BAS 32
#define KD 128
#define ED 128
#define HK 64
#define HO 128
#define NT 3

typedef uint16_t u16;
typedef uint32_t u32;
using bfrag = __attribute__((ext_vector_type(8))) short;  // 8 bf16 = 4 VGPRs
using f32x4 = __attribute__((ext_vector_type(4))) float;

#define MFMA(a, b, c) __builtin_amdgcn_mfma_f32_16x16x32_bf16(a, b, c, 0, 0, 0)

__device__ __forceinline__ short ftob(float f) {
    u32 x = __float_as_uint(f);
    u32 r = x + 0x7fffu + ((x >> 16) & 1u); // RNE
    return (short)(r >> 16);
}
__device__ __forceinline__ float bf2f(u16 u) {
    return __uint_as_float(((u32)u) << 16);
}
// 8 consecutive f32 (global or LDS) -> bf16 A/B fragment
__device__ __forceinline__ bfrag ldf_frag(const float* p) {
    float4 a = *(const float4*)p;
    float4 c = *(const float4*)(p + 4);
    bfrag r;
    r[0] = ftob(a.x); r[1] = ftob(a.y); r[2] = ftob(a.z); r[3] = ftob(a.w);
    r[4] = ftob(c.x); r[5] = ftob(c.y); r[6] = ftob(c.z); r[7] = ftob(c.w);
    return r;
}
// softplus(x) - log(2), numerically stable
__device__ __forceinline__ float ssp_f(float x) {
    float ax = fabsf(x);
    return fmaxf(x, 0.0f) + __logf(1.0f + __expf(-ax)) - 0.6931471805599453f;
}

// One block per batch element; 512 threads = 8 waves; MFMA everywhere.
// Frag conventions (guide §3, m89/m91-verified):
//   A: lane&15 = m, (lane>>4)*8+j = k   |  B: lane&15 = n, (lane>>4)*8+j = k
//   C/D: col = lane&15 (n), row = (lane>>4)*4 + reg (m)
// Weights are [out][in] row-major == B[n][k] directly: no transposes anywhere.
// LDS: xs/zacc f32 stride 132 (A-read bank spread); arena = Hb (wave-private
// C->A transpose, stride 72 u16 = 144B, 16B-aligned) aliased with h2f f32.
__global__ __launch_bounds__(512, 1) void schnet_mfma(
    const float* __restrict__ db_g,   // dists_basis (512,32,36,32)
    const float* __restrict__ ee_g,   // embedding_elec (32,128)
    const float* __restrict__ en_g,   // embedding_nuc (4,128)
    const float* __restrict__ w1_g,   // kernel_w1 (3,64,32)
    const float* __restrict__ b1_g,   // kernel_b1 (3,64)
    const float* __restrict__ w2_g,   // kernel_w2 (3,128,64)
    const float* __restrict__ b2_g,   // kernel_b2 (3,128)
    const float* __restrict__ win_g,  // embed_in_w (3,128,128)
    const float* __restrict__ wo1_g,  // embed_out_w1 (3,128,128)
    const float* __restrict__ bo1_g,  // embed_out_b1 (3,128)
    const float* __restrict__ wo2_g,  // embed_out_w2 (3,128,128)
    const float* __restrict__ bo2_g,  // embed_out_b2 (3,128)
    float* __restrict__ out_g)        // (512,32,128) f32
{
    __shared__ __align__(16) float xs[NE * 132];    // residual, f32
    __shared__ __align__(16) float zacc[NE * 132];  // neighbor-sum acc, f32
    __shared__ __align__(16) u16 zsb[NA * 128];     // zs, bf16
    __shared__ __align__(16) u16 arena[8 * 16 * 72]; // Hb | h2f(f32 32x132)
    float* h2f = (float*)arena;

    const int tid = threadIdx.x;
    const int b = blockIdx.x;
    const int w = tid >> 6;   // wave 0..7
    const int l = tid & 63;
    const int lm = l & 15;    // m/n lane index
    const int lq = l >> 4;    // quad 0..3

    // ---- init: xs <- embedding_elec (f32), zsb nuc rows <- embedding_nuc ----
    {
        int idx = tid * 8;
        float4 v0 = *(const float4*)(ee_g + idx);
        float4 v1 = *(const float4*)(ee_g + idx + 4);
        int row = idx >> 7, col = idx & 127;
        *(float4*)&xs[row * 132 + col] = v0;
        *(float4*)&xs[row * 132 + col + 4] = v1;
    }
    if (tid < 64) {
        int idx = tid * 8;
        int row = NE + (idx >> 7), col = idx & 127;
        float4 v0 = *(const float4*)(en_g + idx);
        float4 v1 = *(const float4*)(en_g + idx + 4);
        float f[8] = {v0.x, v0.y, v0.z, v0.w, v1.x, v1.y, v1.z, v1.w};
#pragma unroll
        for (int i = 0; i < 8; i++) zsb[row * 128 + col + i] = (u16)ftob(f[i]);
    }
    __syncthreads();

    for (int t = 0; t < NT; t++) {
        // ---- per-t weight fragments (registers, loaded from global) ----
        bfrag w1f[4], w2f[8][2];
        float b1v[4], b2v[8];
#pragma unroll
        for (int n = 0; n < 4; n++) {
            w1f[n] = ldf_frag(w1_g + (size_t)(t * HK + n * 16 + lm) * BAS + lq * 8);
            b1v[n] = b1_g[t * HK + n * 16 + lm];
        }
#pragma unroll
        for (int n = 0; n < 8; n++) {
#pragma unroll
            for (int s = 0; s < 2; s++)
                w2f[n][s] = ldf_frag(w2_g + (size_t)(t * KD + n * 16 + lm) * HK + s * 32 + lq * 8);
            b2v[n] = b2_g[t * KD + n * 16 + lm];
        }

        // ---- phase A: zs[e][k] = xs . win^T   (M=32,N=128,K=128) ----
        // wave w owns n-tile w (cols w*16..+15); m-tiles 0,1.
        {
            bfrag wb[4];
#pragma unroll
            for (int ks = 0; ks < 4; ks++)
                wb[ks] = ldf_frag(win_g + (size_t)(t * KD + w * 16 + lm) * ED + ks * 32 + lq * 8);
            f32x4 c[2];
            c[0] = (f32x4){0.f, 0.f, 0.f, 0.f};
            c[1] = (f32x4){0.f, 0.f, 0.f, 0.f};
#pragma unroll
            for (int m = 0; m < 2; m++)
#pragma unroll
                for (int ks = 0; ks < 4; ks++) {
                    bfrag a = ldf_frag(&xs[(m * 16 + lm) * 132 + ks * 32 + lq * 8]);
                    c[m] = MFMA(a, wb[ks], c[m]);
                }
            // zero zacc while MFMAs are in flight
            for (int i = tid; i < NE * 132; i += 512) zacc[i] = 0.f;
#pragma unroll
            for (int m = 0; m < 2; m++)
#pragma unroll
                for (int r = 0; r < 4; r++)
                    zsb[(m * 16 + lq * 4 + r) * 128 + w * 16 + lm] = (u16)ftob(c[m][r]);
        }
        __syncthreads();

        // ---- pair loop: 70 m-tiles of 16 pairs, wave-parallel, no barriers ----
        u16* hb = arena + w * (16 * 72); // wave-private H transpose buffer
        for (int mt = w; mt < 70; mt += 8) {
            // GEMM1 A-frag straight from global db (bf16 cvt)
            int p = mt * 16 + lm;
            int e = p / 35, jj = p - e * 35;
            int j = jj + (jj >= e);
            bfrag ad = ldf_frag(db_g + ((size_t)(b * NE + e) * NA + j) * BAS + lq * 8);
            // GEMM1: H = ssp(db . w1^T + b1)  (16x64, K=32 = one MFMA step)
            f32x4 c1[4];
#pragma unroll
            for (int n = 0; n < 4; n++) {
                c1[n] = (f32x4){0.f, 0.f, 0.f, 0.f};
                c1[n] = MFMA(ad, w1f[n], c1[n]);
            }
            // C-layout -> A-layout transpose via wave-private LDS
#pragma unroll
            for (int n = 0; n < 4; n++)
#pragma unroll
                for (int r = 0; r < 4; r++)
                    hb[(lq * 4 + r) * 72 + n * 16 + lm] =
                        (u16)ftob(ssp_f(c1[n][r] + b1v[n]));
            bfrag a2[2];
#pragma unroll
            for (int s = 0; s < 2; s++)
                a2[s] = *(const bfrag*)&hb[lm * 72 + s * 32 + lq * 8];
            // GEMM2: Ws = H . w2^T  (16x128, K=64)
            f32x4 c2[8];
#pragma unroll
            for (int n = 0; n < 8; n++) c2[n] = (f32x4){0.f, 0.f, 0.f, 0.f};
#pragma unroll
            for (int s = 0; s < 2; s++)
#pragma unroll
                for (int n = 0; n < 8; n++) c2[n] = MFMA(a2[s], w2f[n][s], c2[n]);
            // consume: zacc[e][k] += (Ws + b2) * zs[j][k]
#pragma unroll
            for (int r = 0; r < 4; r++) {
                int pr = mt * 16 + lq * 4 + r;
                int er = pr / 35, jjr = pr - er * 35;
                int jr = jjr + (jjr >= er);
#pragma unroll
                for (int n = 0; n < 8; n++) {
                    int k = n * 16 + lm;
                    float val = (c2[n][r] + b2v[n]) * bf2f(zsb[jr * 128 + k]);
                    atomicAdd(&zacc[er * 132 + k], val);
                }
            }
        }
        __syncthreads();

        // ---- D1: h2 = ssp(zacc . wo1^T + bo1)  (M=32,N=128,K=128) ----
        {
            bfrag wb[4];
#pragma unroll
            for (int ks = 0; ks < 4; ks++)
                wb[ks] = ldf_frag(wo1_g + (size_t)(t * HO + w * 16 + lm) * KD + ks * 32 + lq * 8);
            float bo1v = bo1_g[t * HO + w * 16 + lm];
            f32x4 c[2];
            c[0] = (f32x4){0.f, 0.f, 0.f, 0.f};
            c[1] = (f32x4){0.f, 0.f, 0.f, 0.f};
#pragma unroll
            for (int m = 0; m < 2; m++)
#pragma unroll
                for (int ks = 0; ks < 4; ks++) {
                    bfrag a = ldf_frag(&zacc[(m * 16 + lm) * 132 + ks * 32 + lq * 8]);
                    c[m] = MFMA(a, wb[ks], c[m]);
                }
#pragma unroll
            for (int m = 0; m < 2; m++)
#pragma unroll
                for (int r = 0; r < 4; r++)
                    h2f[(m * 16 + lq * 4 + r) * 132 + w * 16 + lm] =
                        ssp_f(c[m][r] + bo1v);
        }
        __syncthreads();

        // ---- D2: xs += h2 . wo2^T + bo2  (M=32,N=128,K=128) ----
        {
            bfrag wb[4];
#pragma unroll
            for (int ks = 0; ks < 4; ks++)
                wb[ks] = ldf_frag(wo2_g + (size_t)(t * ED + w * 16 + lm) * HO + ks * 32 + lq * 8);
            float bo2v = bo2_g[t * ED + w * 16 + lm];
            f32x4 c[2];
            c[0] = (f32x4){0.f, 0.f, 0.f, 0.f};
            c[1] = (f32x4){0.f, 0.f, 0.f, 0.f};
#pragma unroll
            for (int m = 0; m < 2; m++)
#pragma unroll
                for (int ks = 0; ks < 4; ks++) {
                    bfrag a = ldf_frag(&h2f[(m * 16 + lm) * 132 + ks * 32 + lq * 8]);
                    c[m] = MFMA(a, wb[ks], c[m]);
                }
#pragma unroll
            for (int m = 0; m < 2; m++)
#pragma unroll
                for (int r = 0; r < 4; r++) {
                    int row = m * 16 + lq * 4 + r, col = w * 16 + lm;
                    xs[row * 132 + col] += c[m][r] + bo2v;
                }
        }
        __syncthreads();
    }

    // ---- write out (f32, coalesced float4) ----
#pragma unroll
    for (int ii = 0; ii < 2; ii++) {
        int idx = (ii * 512 + tid) * 4;
        int row = idx >> 7, col = idx & 127;
        *(float4*)&out_g[(size_t)b * (NE * ED) + idx] = *(const float4*)&xs[row * 132 + col];
    }
}

extern "C" void kernel_launch(void* const* d_in, const int* in_sizes, int n_in,
                              void* d_out, int out_size, void* d_ws, size_t ws_size,
                              hipStream_t stream) {
    schnet_mfma<<<NBATCH, 512, 0, stream>>>(
        (const float*)d_in[0], (const float*)d_in[1], (const float*)d_in[2],
        (const float*)d_in[3], (const float*)d_in[4], (const float*)d_in[5],
        (const float*)d_in[6], (const float*)d_in[7], (const float*)d_in[8],
        (const float*)d_in[9], (const float*)d_in[10], (const float*)d_in[11],
        (float*)d_out);
}